// Round 5
// baseline (115.232 us; speedup 1.0000x reference)
//
#include <hip/hip_runtime.h>
#include <hip/hip_bf16.h>

#define DD 128
#define NEGS 0.01f

typedef float  f32x4 __attribute__((ext_vector_type(4)));
typedef __bf16 bf16x8 __attribute__((ext_vector_type(8)));
typedef unsigned short us8 __attribute__((ext_vector_type(8)));

__device__ __forceinline__ unsigned short f2bf(float f) {
    unsigned int u = __builtin_bit_cast(unsigned int, f);
    u += 0x7FFFu + ((u >> 16) & 1u);          // RNE (no NaN inputs here)
    return (unsigned short)(u >> 16);
}
__device__ __forceinline__ float bflo(unsigned int u) {
    return __builtin_bit_cast(float, u << 16);
}
__device__ __forceinline__ float bfhi(unsigned int u) {
    return __builtin_bit_cast(float, u & 0xFFFF0000u);
}

// -------- aux: blocks [0,64): W fp32->bf16 ; blocks [64,..): segment starts --
__global__ __launch_bounds__(256)
void k_aux(const float* __restrict__ W, unsigned short* __restrict__ W16,
           const int* __restrict__ dst, int E, int N, int* __restrict__ start)
{
    int b = blockIdx.x;
    if (b < 64) {
        int i = b * 256 + threadIdx.x;
        W16[i] = f2bf(W[i]);
    } else {
        int n = (b - 64) * 256 + threadIdx.x;
        if (n > N) return;
        int lo = 0, hi = E;
        while (lo < hi) {
            int mid = (lo + hi) >> 1;
            if (dst[mid] < n) lo = mid + 1; else hi = mid;
        }
        start[n] = lo;
    }
}

// ---------- fused GEMM + logits: z16 = bf16(h @ W^T), ll/lr = z @ a --------
// One wave computes 16 rows of z (1 row-tile x 8 col-tiles, K=128).
// C/D mapping: col = lane&15, row = (lane>>4)*4 + reg   [m89 verified]
__global__ __launch_bounds__(256)
void k_gemm_mfma(const float* __restrict__ h, const unsigned short* __restrict__ W16,
                 const float* __restrict__ attn,
                 unsigned short* __restrict__ z16,
                 float* __restrict__ ll, float* __restrict__ lr, int N)
{
    const int lane = threadIdx.x & 63;
    const int gw   = (blockIdx.x * 256 + threadIdx.x) >> 6;
    const int i0   = gw * 16;
    if (i0 >= N) return;
    const int hl = lane & 15;
    const int g  = lane >> 4;
    const int ko = g * 8;

    int r0 = i0 + hl; if (r0 > N - 1) r0 = N - 1;   // clamp loads; stores guarded

    f32x4 acc[8];
#pragma unroll
    for (int jt = 0; jt < 8; ++jt) acc[jt] = f32x4{0.f, 0.f, 0.f, 0.f};

#pragma unroll
    for (int kk = 0; kk < DD; kk += 32) {
        const float* pa = h + (size_t)r0 * DD + kk + ko;
        float4 va = *(const float4*)pa, vb = *(const float4*)(pa + 4);
        us8 ua = { f2bf(va.x), f2bf(va.y), f2bf(va.z), f2bf(va.w),
                   f2bf(vb.x), f2bf(vb.y), f2bf(vb.z), f2bf(vb.w) };
        bf16x8 a = __builtin_bit_cast(bf16x8, ua);
#pragma unroll
        for (int jt = 0; jt < 8; ++jt) {
            us8 ub = *(const us8*)(W16 + (size_t)(jt * 16 + hl) * DD + kk + ko);
            bf16x8 b = __builtin_bit_cast(bf16x8, ub);
            acc[jt] = __builtin_amdgcn_mfma_f32_16x16x32_bf16(a, b, acc[jt], 0, 0, 0);
        }
    }

    float aLc[8], aRc[8];
#pragma unroll
    for (int jt = 0; jt < 8; ++jt) {
        aLc[jt] = attn[jt * 16 + hl];
        aRc[jt] = attn[DD + jt * 16 + hl];
    }
#pragma unroll
    for (int reg = 0; reg < 4; ++reg) {
        const int row = i0 + g * 4 + reg;
        float pl = 0.f, pr = 0.f;
#pragma unroll
        for (int jt = 0; jt < 8; ++jt) {
            float v = acc[jt][reg];
            pl = fmaf(v, aLc[jt], pl);
            pr = fmaf(v, aRc[jt], pr);
        }
#pragma unroll
        for (int o = 8; o >= 1; o >>= 1) {
            pl += __shfl_xor(pl, o);
            pr += __shfl_xor(pr, o);
        }
        if (row < N) {
            if (hl == 0) { ll[row] = pl; lr[row] = pr; }
            unsigned short* zr = z16 + (size_t)row * DD;
#pragma unroll
            for (int jt = 0; jt < 8; ++jt)
                zr[jt * 16 + hl] = f2bf(acc[jt][reg]);
        }
    }
}

// ------- edge weights, packed: pw[j] = {src[j], bits(exp(leaky(...)))} ------
__global__ __launch_bounds__(256)
void k_ew(const int* __restrict__ src, const int* __restrict__ dst,
          const float* __restrict__ ll, const float* __restrict__ lr,
          uint2* __restrict__ pw, int E)
{
    int j = blockIdx.x * 256 + threadIdx.x;
    if (j >= E) return;
    int s = src[j];
    float v = ll[s] + lr[dst[j]];
    float e = (v >= 0.f) ? v : NEGS * v;
    pw[j] = make_uint2((unsigned)s, __builtin_bit_cast(unsigned, __expf(e)));
}

// ---------------- output, XCD-sliced -------------------------------------
// blockIdx%8 = XCD (empirical round-robin). XCD x gathers only z16 columns
// [32*(x&3), 32*(x&3)+32) -> a 64 B line per edge, 3.2 MB working set that
// fits the XCD's private 4 MB L2. Half x>>2 selects the node range.
// Wave = node; quarter q handles edges base+q, base+q+4; 16 lanes x 4 B = line.
__global__ __launch_bounds__(256)
void k_out(const unsigned short* __restrict__ z16, const uint2* __restrict__ pw,
           const int* __restrict__ start, float* __restrict__ out, int N, int Nh)
{
    const int xcd   = blockIdx.x & 7;
    const int slice = xcd & 3;
    const int half  = xcd >> 2;
    const int wv    = threadIdx.x >> 6;
    const int node  = half * Nh + (blockIdx.x >> 3) * 4 + wv;
    const int lane  = threadIdx.x & 63;
    const int hiN   = min(N, half * Nh + Nh);
    if (node >= hiN) return;
    const int q = lane >> 4;      // quarter 0..3
    const int c = lane & 15;      // dword c of the 64 B slice line

    const int s0 = start[node], s1 = start[node + 1];
    const int last = s1 - 1;
    const unsigned short* zs = z16 + slice * 32 + c * 2;

    float a0 = 0.f, a1 = 0.f, ssum = 0.f;
    for (int base = s0; base < s1; base += 8) {
        int t0 = base + q;
        int t1 = t0 + 4;
        int tc0 = (t0 <= last) ? t0 : last;
        int tc1 = (t1 <= last) ? t1 : last;
        uint2 p0 = pw[tc0];
        uint2 p1 = pw[tc1];
        float w0 = __builtin_bit_cast(float, p0.y); if (t0 > last) w0 = 0.f;
        float w1 = __builtin_bit_cast(float, p1.y); if (t1 > last) w1 = 0.f;
        unsigned int zv0 = *(const unsigned int*)(zs + (size_t)p0.x * DD);
        unsigned int zv1 = *(const unsigned int*)(zs + (size_t)p1.x * DD);
        ssum += w0 + w1;
        a0 = fmaf(w0, bflo(zv0), fmaf(w1, bflo(zv1), a0));
        a1 = fmaf(w0, bfhi(zv0), fmaf(w1, bfhi(zv1), a1));
    }
    // combine the 4 quarters (lanes {l, l^16, l^32, l^48} share a dword slot)
    a0 += __shfl_xor(a0, 16);  a0 += __shfl_xor(a0, 32);
    a1 += __shfl_xor(a1, 16);  a1 += __shfl_xor(a1, 32);
    ssum += __shfl_xor(ssum, 16);  ssum += __shfl_xor(ssum, 32);
    float inv = (s1 > s0) ? 1.0f / ssum : 0.f;   // empty segment -> zeros

    if (q == 0) {
        float2 o = make_float2(a0 * inv, a1 * inv);
        *(float2*)(out + (size_t)node * DD + slice * 32 + c * 2) = o;
    }
}

extern "C" void kernel_launch(void* const* d_in, const int* in_sizes, int n_in,
                              void* d_out, int out_size, void* d_ws, size_t ws_size,
                              hipStream_t stream) {
    const float* h    = (const float*)d_in[0];
    const int*   src  = (const int*)d_in[1];
    const int*   dst  = (const int*)d_in[2];
    const float* W    = (const float*)d_in[3];
    const float* attn = (const float*)d_in[4];
    const int N = in_sizes[0] / DD;
    const int E = in_sizes[1];
    float* out = (float*)d_out;

    // workspace layout (pw first-aligned: N*256 bytes is 8B-aligned)
    unsigned short* z16 = (unsigned short*)d_ws;          // N*128 bf16 (12.8 MB)
    uint2* pw  = (uint2*)(z16 + (size_t)N * DD);          // E uint2 (6.4 MB)
    float* ll  = (float*)(pw + E);                        // N
    float* lr  = ll + N;                                  // N
    int* start = (int*)(lr + N);                          // N+1
    unsigned short* W16 = (unsigned short*)(start + N + 1); // 16384

    const int Nh = (N + 1) / 2;

    k_aux<<<64 + (N + 1 + 255) / 256, 256, 0, stream>>>(W, W16, dst, E, N, start);
    k_gemm_mfma<<<(N + 63) / 64, 256, 0, stream>>>(h, W16, attn, z16, ll, lr, N);
    k_ew<<<(E + 255) / 256, 256, 0, stream>>>(src, dst, ll, lr, pw, E);
    k_out<<<8 * ((Nh + 3) / 4), 256, 0, stream>>>(z16, pw, start, out, N, Nh);
}

// Round 7
// 68.583 us; speedup vs baseline: 1.6802x; 1.6802x over previous
//
#include <hip/hip_runtime.h>
#include <hip/hip_bf16.h>

#define DD 128
#define NEGS 0.01f

typedef float  f32x4 __attribute__((ext_vector_type(4)));
typedef __bf16 bf16x8 __attribute__((ext_vector_type(8)));
typedef unsigned short us8 __attribute__((ext_vector_type(8)));

__device__ __forceinline__ unsigned short f2bf(float f) {
    unsigned int u = __builtin_bit_cast(unsigned int, f);
    u += 0x7FFFu + ((u >> 16) & 1u);          // RNE (no NaN inputs here)
    return (unsigned short)(u >> 16);
}
__device__ __forceinline__ float bflo(unsigned int u) {
    return __builtin_bit_cast(float, u << 16);
}
__device__ __forceinline__ float bfhi(unsigned int u) {
    return __builtin_bit_cast(float, u & 0xFFFF0000u);
}

// -------- aux: blocks [0,64): W fp32->bf16 ; blocks [64,..): segment starts --
__global__ __launch_bounds__(256)
void k_aux(const float* __restrict__ W, unsigned short* __restrict__ W16,
           const int* __restrict__ dst, int E, int N, int* __restrict__ start)
{
    int b = blockIdx.x;
    if (b < 64) {
        int i = b * 256 + threadIdx.x;
        W16[i] = f2bf(W[i]);
    } else {
        int n = (b - 64) * 256 + threadIdx.x;
        if (n > N) return;
        int lo = 0, hi = E;
        while (lo < hi) {
            int mid = (lo + hi) >> 1;
            if (dst[mid] < n) lo = mid + 1; else hi = mid;
        }
        start[n] = lo;
    }
}

// ---------- fused GEMM + logits: z16 = bf16(h @ W^T), ll/lr = z @ a --------
// One wave computes 16 rows of z (1 row-tile x 8 col-tiles, K=128).
// C/D mapping: col = lane&15, row = (lane>>4)*4 + reg   [m89 verified]
__global__ __launch_bounds__(256)
void k_gemm_mfma(const float* __restrict__ h, const unsigned short* __restrict__ W16,
                 const float* __restrict__ attn,
                 unsigned short* __restrict__ z16,
                 float* __restrict__ ll, float* __restrict__ lr, int N)
{
    const int lane = threadIdx.x & 63;
    const int gw   = (blockIdx.x * 256 + threadIdx.x) >> 6;
    const int i0   = gw * 16;
    if (i0 >= N) return;
    const int hl = lane & 15;
    const int g  = lane >> 4;
    const int ko = g * 8;

    int r0 = i0 + hl; if (r0 > N - 1) r0 = N - 1;   // clamp loads; stores guarded

    f32x4 acc[8];
#pragma unroll
    for (int jt = 0; jt < 8; ++jt) acc[jt] = f32x4{0.f, 0.f, 0.f, 0.f};

#pragma unroll
    for (int kk = 0; kk < DD; kk += 32) {
        const float* pa = h + (size_t)r0 * DD + kk + ko;
        float4 va = *(const float4*)pa, vb = *(const float4*)(pa + 4);
        us8 ua = { f2bf(va.x), f2bf(va.y), f2bf(va.z), f2bf(va.w),
                   f2bf(vb.x), f2bf(vb.y), f2bf(vb.z), f2bf(vb.w) };
        bf16x8 a = __builtin_bit_cast(bf16x8, ua);
#pragma unroll
        for (int jt = 0; jt < 8; ++jt) {
            us8 ub = *(const us8*)(W16 + (size_t)(jt * 16 + hl) * DD + kk + ko);
            bf16x8 b = __builtin_bit_cast(bf16x8, ub);
            acc[jt] = __builtin_amdgcn_mfma_f32_16x16x32_bf16(a, b, acc[jt], 0, 0, 0);
        }
    }

    float aLc[8], aRc[8];
#pragma unroll
    for (int jt = 0; jt < 8; ++jt) {
        aLc[jt] = attn[jt * 16 + hl];
        aRc[jt] = attn[DD + jt * 16 + hl];
    }
#pragma unroll
    for (int reg = 0; reg < 4; ++reg) {
        const int row = i0 + g * 4 + reg;
        float pl = 0.f, pr = 0.f;
#pragma unroll
        for (int jt = 0; jt < 8; ++jt) {
            float v = acc[jt][reg];
            pl = fmaf(v, aLc[jt], pl);
            pr = fmaf(v, aRc[jt], pr);
        }
#pragma unroll
        for (int o = 8; o >= 1; o >>= 1) {
            pl += __shfl_xor(pl, o);
            pr += __shfl_xor(pr, o);
        }
        if (row < N) {
            if (hl == 0) { ll[row] = pl; lr[row] = pr; }
            unsigned short* zr = z16 + (size_t)row * DD;
#pragma unroll
            for (int jt = 0; jt < 8; ++jt)
                zr[jt * 16 + hl] = f2bf(acc[jt][reg]);
        }
    }
}

// ---------------- fused output: w on-the-fly + weighted gather ------------
// wave = node; 4 quarter-waves, 2 edges each per iter (8 edges/iter).
// w = exp(leaky(ll[src]+lr[n])) computed inline (ll is 200 KB, L2-resident;
// quarter lanes broadcast-load the same address). No max-subtraction:
// logits are O(10), exp() fp32-safe, softmax shift-invariant.
// src loads and out stores are non-temporal: keep L2/L3 for z16 + ll.
__global__ __launch_bounds__(256)
void k_out(const unsigned short* __restrict__ z16, const int* __restrict__ src,
           const float* __restrict__ ll, const float* __restrict__ lr,
           const int* __restrict__ start, float* __restrict__ out, int N)
{
    int wid  = (blockIdx.x * 256 + threadIdx.x) >> 6;
    int lane = threadIdx.x & 63;
    if (wid >= N) return;
    const int s0 = start[wid], s1 = start[wid + 1];
    const int q = lane >> 4;      // quarter 0..3
    const int c = lane & 15;      // col block: cols 8c .. 8c+7
    const float lrn = lr[wid];

    float acc[8];
#pragma unroll
    for (int k = 0; k < 8; ++k) acc[k] = 0.f;
    float ssum = 0.f;
    const int last = s1 - 1;

    for (int base = s0; base < s1; base += 8) {
        int t0 = base + q;
        int t1 = t0 + 4;
        int tc0 = (t0 <= last) ? t0 : last;
        int tc1 = (t1 <= last) ? t1 : last;
        int sj0 = __builtin_nontemporal_load(src + tc0);
        int sj1 = __builtin_nontemporal_load(src + tc1);
        float v0 = ll[sj0] + lrn;  v0 = (v0 >= 0.f) ? v0 : NEGS * v0;
        float v1 = ll[sj1] + lrn;  v1 = (v1 >= 0.f) ? v1 : NEGS * v1;
        float w0 = __expf(v0); if (t0 > last) w0 = 0.f;
        float w1 = __expf(v1); if (t1 > last) w1 = 0.f;
        uint4 z0 = *(const uint4*)(z16 + (size_t)sj0 * DD + c * 8);
        uint4 z1 = *(const uint4*)(z16 + (size_t)sj1 * DD + c * 8);
        ssum += w0 + w1;
        acc[0] = fmaf(w0, bflo(z0.x), fmaf(w1, bflo(z1.x), acc[0]));
        acc[1] = fmaf(w0, bfhi(z0.x), fmaf(w1, bfhi(z1.x), acc[1]));
        acc[2] = fmaf(w0, bflo(z0.y), fmaf(w1, bflo(z1.y), acc[2]));
        acc[3] = fmaf(w0, bfhi(z0.y), fmaf(w1, bfhi(z1.y), acc[3]));
        acc[4] = fmaf(w0, bflo(z0.z), fmaf(w1, bflo(z1.z), acc[4]));
        acc[5] = fmaf(w0, bfhi(z0.z), fmaf(w1, bfhi(z1.z), acc[5]));
        acc[6] = fmaf(w0, bflo(z0.w), fmaf(w1, bflo(z1.w), acc[6]));
        acc[7] = fmaf(w0, bfhi(z0.w), fmaf(w1, bfhi(z1.w), acc[7]));
    }
    // combine the 4 quarters (lanes {l, l^16, l^32, l^48} share a col block)
#pragma unroll
    for (int k = 0; k < 8; ++k) {
        acc[k] += __shfl_xor(acc[k], 16);
        acc[k] += __shfl_xor(acc[k], 32);
    }
    ssum += __shfl_xor(ssum, 16);
    ssum += __shfl_xor(ssum, 32);
    float inv = (s1 > s0) ? 1.0f / ssum : 0.f;   // empty segment -> zeros

    float* orow = out + (size_t)wid * DD + c * 8;
    if (q == 0) {
        f32x4 o = {acc[0]*inv, acc[1]*inv, acc[2]*inv, acc[3]*inv};
        __builtin_nontemporal_store(o, (f32x4*)orow);
    } else if (q == 1) {
        f32x4 o = {acc[4]*inv, acc[5]*inv, acc[6]*inv, acc[7]*inv};
        __builtin_nontemporal_store(o, ((f32x4*)orow) + 1);
    }
}

extern "C" void kernel_launch(void* const* d_in, const int* in_sizes, int n_in,
                              void* d_out, int out_size, void* d_ws, size_t ws_size,
                              hipStream_t stream) {
    const float* h    = (const float*)d_in[0];
    const int*   src  = (const int*)d_in[1];
    const int*   dst  = (const int*)d_in[2];
    const float* W    = (const float*)d_in[3];
    const float* attn = (const float*)d_in[4];
    const int N = in_sizes[0] / DD;
    const int E = in_sizes[1];
    float* out = (float*)d_out;

    // workspace layout
    unsigned short* z16 = (unsigned short*)d_ws;          // N*128 bf16 (12.8 MB)
    float* ll  = (float*)(z16 + (size_t)N * DD);          // N
    float* lr  = ll + N;                                  // N
    int* start = (int*)(lr + N);                          // N+1
    unsigned short* W16 = (unsigned short*)(start + N + 1); // 16384

    k_aux<<<64 + (N + 1 + 255) / 256, 256, 0, stream>>>(W, W16, dst, E, N, start);
    k_gemm_mfma<<<(N + 63) / 64, 256, 0, stream>>>(h, W16, attn, z16, ll, lr, N);
    k_out<<<(N + 3) / 4, 256, 0, stream>>>(z16, src, ll, lr, start, out, N);
}